// Round 12
// baseline (297.823 us; speedup 1.0000x reference)
//
#include <hip/hip_runtime.h>
#include <math.h>

#define NXI 320
#define NCI 8
#define NTI 8
#define MI  65536
#define GI  640
#define G2I (GI*GI)
#define NPIX (NXI*NXI)
#define REC_F 20          // floats per record: {du,dv,0,0, 8x(re,im)}
#define NBINS (NTI*G2I)   // 3,276,800 cells over all frames
#define SCAN_BLKS2 (NBINS/4096)   // 800 (4096 bins per block)

typedef float v2f __attribute__((ext_vector_type(2)));

__device__ inline v2f cmul(v2f a, v2f b) {
    v2f axx = __builtin_shufflevector(a, a, 0, 0);
    v2f ayy = __builtin_shufflevector(a, a, 1, 1);
    v2f byx = __builtin_shufflevector(b, b, 1, 0);
    v2f r = axx * b;
    v2f t = ayy * byx;
    return r + v2f{-t.x, t.y};
}

__device__ inline v2f shfl_xor_v(v2f v, int m) {
    return v2f{__shfl_xor(v.x, m, 64), __shfl_xor(v.y, m, 64)};
}

__device__ inline void cell_of(const float* __restrict__ traj, int m, int f,
                               int& i0s, int& j0s, float& du, float& dv)
{
    float tu = traj[(m*2 + 0)*NTI + f];
    float tv = traj[(m*2 + 1)*NTI + f];
    float u = (tu + 0.5f) * (float)GI;
    float v = (tv + 0.5f) * (float)GI;
    float fu = floorf(u), fv = floorf(v);
    du = u - fu; dv = v - fv;
    i0s = (int)fu + GI/2; if (i0s >= GI) i0s -= GI;   // ifftshift folded in
    j0s = (int)fv + GI/2; if (j0s >= GI) j0s -= GI;
}

// ---------------- cell-level counting sort, all frames ----------------
__global__ __launch_bounds__(256) void count_cells(
    const float* __restrict__ traj, int* __restrict__ counts)
{
    int tid = blockIdx.x * 256 + threadIdx.x;   // f*MI + m
    int f = tid >> 16, m = tid & (MI - 1);
    int i0s, j0s; float du, dv;
    cell_of(traj, m, f, i0s, j0s, du, dv);
    atomicAdd(&counts[f*G2I + i0s*GI + j0s], 1);
}

__device__ inline int wave_incl_scan(int v, int lane) {
    #pragma unroll
    for (int d = 1; d < 64; d <<= 1) {
        int y = __shfl_up(v, d, 64);
        if (lane >= d) v += y;
    }
    return v;
}

// 4096 bins per block, barrier-light: wave shuffle scan + 16-entry cross-wave
__global__ __launch_bounds__(1024) void scanA(const int4* __restrict__ counts4,
                                              int4* __restrict__ binstart4,
                                              int* __restrict__ sums)
{
    __shared__ int wtot[16];
    int tid = threadIdx.x, lane = tid & 63, wv = tid >> 6;
    int i = blockIdx.x * 1024 + tid;
    int4 c = counts4[i];
    int s = c.x + c.y + c.z + c.w;
    int incl = wave_incl_scan(s, lane);
    if (lane == 63) wtot[wv] = incl;
    __syncthreads();
    if (wv == 0 && lane < 16) {
        int t = wtot[lane];
        #pragma unroll
        for (int d = 1; d < 16; d <<= 1) {
            int y = __shfl_up(t, d, 64);
            if (lane >= d) t += y;
        }
        wtot[lane] = t;     // inclusive over waves
    }
    __syncthreads();
    int woff = wv ? wtot[wv - 1] : 0;
    int excl = woff + incl - s;
    int4 b;
    b.x = excl; b.y = excl + c.x; b.z = b.y + c.y; b.w = b.z + c.z;
    binstart4[i] = b;
    if (tid == 1023) sums[blockIdx.x] = woff + incl;   // block total
}

// one block: exclusive scan of the 800 chunk sums + sentinels
__global__ __launch_bounds__(1024) void scanB(int* __restrict__ sums,
                                              int* __restrict__ binstart)
{
    __shared__ int tmp[1024];
    int tid = threadIdx.x;
    int v = (tid < SCAN_BLKS2) ? sums[tid] : 0;
    tmp[tid] = v; __syncthreads();
    for (int d = 1; d < 1024; d <<= 1) {
        int y = (tid >= d) ? tmp[tid - d] : 0;
        __syncthreads();
        tmp[tid] += y;
        __syncthreads();
    }
    int incl = tmp[tid];
    if (tid < SCAN_BLKS2) sums[tid] = incl - v;
    if (tid == SCAN_BLKS2 - 1) {
        sums[SCAN_BLKS2] = incl;        // == grand total: sentinel chunk
        binstart[NBINS] = 0;            // so GS(NBINS) == total
    }
}

// slot via atomicSub on counts — no cursor array
__global__ __launch_bounds__(256) void scatter_cells(
    const float* __restrict__ kr, const float* __restrict__ ki,
    const float* __restrict__ traj, const float* __restrict__ dcf,
    int* __restrict__ counts, const int* __restrict__ binstart,
    const int* __restrict__ sums, float* __restrict__ recs)
{
    int tid = blockIdx.x * 256 + threadIdx.x;   // f*MI + m
    int f = tid >> 16, m = tid & (MI - 1);
    int i0s, j0s; float du, dv;
    cell_of(traj, m, f, i0s, j0s, du, dv);
    float w = dcf[m*NTI + f];
    int bin = f*G2I + i0s*GI + j0s;
    int within = atomicSub(&counts[bin], 1) - 1;
    int slot = binstart[bin] + sums[bin >> 12] + within;
    float4* r = (float4*)(recs + (size_t)slot * REC_F);
    r[0] = make_float4(du, dv, 0.f, 0.f);
    #pragma unroll
    for (int q = 0; q < 4; ++q) {
        int c0 = 2*q;
        r[1+q] = make_float4(kr[c0*MI + m]*w,     ki[c0*MI + m]*w,
                             kr[(c0+1)*MI + m]*w, ki[(c0+1)*MI + m]*w);
    }
}

// ---------------- register-resident 640-pt iFFT (sign +), packed ----------------
__device__ inline void dft5p(v2f x0, v2f x1, v2f x2, v2f x3, v2f x4, v2f* X)
{
    const float c1 = 0.309016994f, c2 = -0.809016994f;
    const float s1 = 0.951056516f, s2 =  0.587785252f;
    v2f S1 = x1 + x4, D1 = x1 - x4;
    v2f S2 = x2 + x3, D2 = x2 - x3;
    X[0] = x0 + S1 + S2;
    v2f A = x0 + c1*S1 + c2*S2;
    v2f T = s1*D1 + s2*D2;
    v2f B = x0 + c2*S1 + c1*S2;
    v2f U = s2*D1 - s1*D2;
    v2f iT = v2f{-T.y, T.x};
    v2f iU = v2f{-U.y, U.x};
    X[1] = A + iT;  X[4] = A - iT;
    X[2] = B + iU;  X[3] = B - iU;
}

__device__ inline void fft640_pruned(v2f* a, int lane, v2f* line, int xorm)
{
    const float PI = 3.14159265358979f;
    // 6 across-lane DIF stages: t = p + sg*a (pk_fma), then cmul by
    // hoisted per-lane w (w=1 for low lanes). r5-verified sign convention.
    #pragma unroll
    for (int s = 0; s < 6; ++s) {
        const int h = 32 >> s;
        bool low = (lane & h) == 0;
        int kp = (lane << s) & 31;
        float sn, cs;
        __sincosf((2.0f * PI / 64.0f) * (float)kp, &sn, &cs);
        v2f w = low ? v2f{1.f, 0.f} : v2f{cs, sn};
        float sg = low ? 1.f : -1.f;
        v2f sgv = v2f{sg, sg};
        #pragma unroll
        for (int n = 0; n < 10; ++n) {
            v2f p = shfl_xor_v(a[n], h);
            v2f t = sgv * a[n] + p;        // low: p+a ; high: p-a
            a[n] = cmul(t, w);
        }
    }
    int k1 = __brev(lane) >> 26;
    float th2 = (2.0f * PI / 640.0f) * (float)k1;
    float sn, cs;
    __sincosf(th2, &sn, &cs);
    v2f wb = v2f{cs, sn};
    v2f w = wb;
    #pragma unroll
    for (int n = 1; n < 10; ++n) {
        a[n] = cmul(a[n], w);
        w = cmul(w, wb);
    }
    v2f E[5], O[5];
    dft5p(a[0], a[2], a[4], a[6], a[8], E);
    dft5p(a[1], a[3], a[5], a[7], a[9], O);
    const v2f tk1 = { 0.809016994f, 0.587785252f};
    const v2f tk2 = { 0.309016994f, 0.951056516f};
    const v2f tk3 = {-0.309016994f, 0.951056516f};
    const v2f tk4 = {-0.809016994f, 0.587785252f};
    v2f t1 = cmul(tk1, O[1]);
    v2f t2 = cmul(tk2, O[2]);
    v2f t3 = cmul(tk3, O[3]);
    v2f t4 = cmul(tk4, O[4]);
    bool hi = (k1 >= 32);
    line[(160 + k1) ^ xorm] = E[0] + O[0];          // k2=0
    line[(224 + k1) ^ xorm] = E[1] + t1;            // k2=1
    int yx = hi ? (k1 - 32) : (288 + k1);           // k2=7 : k2=2
    v2f zx = hi ? (E[2] - t2) : (E[2] + t2);
    line[yx ^ xorm] = zx;
    line[(32 + k1) ^ xorm] = E[3] - t3;             // k2=8
    line[(96 + k1) ^ xorm] = E[4] - t4;             // k2=9
}

// ---- fused atomic-free gather + row FFT: block = (frame, grid-row i) ----
// gather j-assignment is WAVE-BALANCED: wave wv owns j in [wv*80, wv*80+80)
__global__ __launch_bounds__(512, 8) void row_fft(
    const int* __restrict__ binstart, const int* __restrict__ sums,
    const float* __restrict__ recs, v2f* __restrict__ rowout)
{
    __shared__ v2f A[NCI][GI];      // 40,960 B exactly -> 4 blocks/CU
    int bid = blockIdx.x;           // f*GI + i
    int i = bid % GI;
    int f = bid / GI;
    int tid = threadIdx.x;
    int wv = tid >> 6, lane = tid & 63;
    int im1 = i ? i - 1 : GI - 1;
    const int base0 = f*G2I + i*GI;     // p=0: row i   (1-du)
    const int base1 = f*G2I + im1*GI;   // p=1: row i-1 (du)

    #define GS(b) (binstart[b] + sums[(b) >> 12])

    #pragma unroll
    for (int q = 0; q < 2; ++q) {
        int j = wv*80 + q*64 + lane;
        if (q == 1 && lane >= 16) break;    // 80 j's per wave: 64 + 16
        v2f acc[NCI];
        #pragma unroll
        for (int c = 0; c < NCI; ++c) acc[c] = v2f{0.f, 0.f};
        #pragma unroll
        for (int p = 0; p < 2; ++p) {
            const int base = p ? base1 : base0;
            if (j > 0) {
                int lo = GS(base + j - 1), mid = GS(base + j), hi = GS(base + j + 1);
                for (int s = lo; s < hi; ++s) {
                    const float4* R = (const float4*)(recs + (size_t)s*REC_F);
                    float4 h4 = R[0];
                    float wr = p ? h4.x : (1.f - h4.x);
                    float w  = wr * ((s < mid) ? h4.y : (1.f - h4.y));
                    float4 d0 = R[1], d1 = R[2], d2 = R[3], d3 = R[4];
                    acc[0] += w * v2f{d0.x, d0.y};  acc[1] += w * v2f{d0.z, d0.w};
                    acc[2] += w * v2f{d1.x, d1.y};  acc[3] += w * v2f{d1.z, d1.w};
                    acc[4] += w * v2f{d2.x, d2.y};  acc[5] += w * v2f{d2.z, d2.w};
                    acc[6] += w * v2f{d3.x, d3.y};  acc[7] += w * v2f{d3.z, d3.w};
                }
            } else {
                #pragma unroll
                for (int side = 0; side < 2; ++side) {
                    int b = base + (side ? 0 : (GI - 1));
                    int s0 = GS(b), s1 = GS(b + 1);
                    for (int s = s0; s < s1; ++s) {
                        const float4* R = (const float4*)(recs + (size_t)s*REC_F);
                        float4 h4 = R[0];
                        float wr = p ? h4.x : (1.f - h4.x);
                        float w  = wr * (side ? (1.f - h4.y) : h4.y);
                        float4 d0 = R[1], d1 = R[2], d2 = R[3], d3 = R[4];
                        acc[0] += w * v2f{d0.x, d0.y};  acc[1] += w * v2f{d0.z, d0.w};
                        acc[2] += w * v2f{d1.x, d1.y};  acc[3] += w * v2f{d1.z, d1.w};
                        acc[4] += w * v2f{d2.x, d2.y};  acc[5] += w * v2f{d2.z, d2.w};
                        acc[6] += w * v2f{d3.x, d3.y};  acc[7] += w * v2f{d3.z, d3.w};
                    }
                }
            }
        }
        #pragma unroll
        for (int c = 0; c < NCI; ++c) A[c][j] = acc[c];
    }
    #undef GS
    __syncthreads();

    v2f a[10];
    #pragma unroll
    for (int n = 0; n < 10; ++n) a[n] = A[wv][10*lane + n];
    fft640_pruned(a, lane, A[wv], 0);
    v2f* dst = rowout + (((size_t)f*NCI + wv)*GI + i)*NXI;
    #pragma unroll
    for (int q = 0; q < 5; ++q) {
        int yc = lane + 64*q;
        dst[yc] = A[wv][yc];
    }
}

// ---- col FFT + crop: block = (frame, coil, y-group of 8) ----
__global__ __launch_bounds__(512, 8) void col_fft(
    const v2f* __restrict__ rowout, v2f* __restrict__ colimg)
{
    __shared__ v2f A[8][GI];
    int bid = blockIdx.x;
    int g = bid % 40;
    int c = (bid / 40) % NCI;
    int f = bid / (40*NCI);
    int y0 = g * 8;
    int tid = threadIdx.x;
    const v2f* src = rowout + ((size_t)f*NCI + c)*GI*NXI + y0;
    for (int idx = tid; idx < 8*GI; idx += 512) {
        int l = idx & 7, k = idx >> 3;
        A[l][k ^ (4*(l & 3))] = src[(size_t)k*NXI + l];
    }
    __syncthreads();
    int wv = tid >> 6, lane = tid & 63;
    int xm = 4 * (wv & 3);
    v2f a[10];
    #pragma unroll
    for (int n = 0; n < 10; ++n) a[n] = A[wv][(10*lane + n) ^ xm];
    fft640_pruned(a, lane, A[wv], xm);
    __syncthreads();
    v2f* dst = colimg + ((size_t)f*NCI + c)*NPIX + y0;
    for (int idx = tid; idx < 8*NXI; idx += 512) {
        int l = idx & 7, xx = idx >> 3;
        dst[(size_t)xx*NXI + l] = A[l][xx ^ (4*(l & 3))];
    }
}

// ------------- deapodize + coil combine -------------
__global__ __launch_bounds__(256) void combine_kernel(
    const float2* __restrict__ colimg, const float* __restrict__ csr,
    const float* __restrict__ csi, float2* __restrict__ img)
{
    int f = blockIdx.y;
    int pix = blockIdx.x * 256 + threadIdx.x;
    int x = pix / NXI, y = pix - x*NXI;
    const float PI = 3.14159265358979f;
    float tx = (x - 160) * (1.0f/GI);
    float ty = (y - 160) * (1.0f/GI);
    float dx = 1.0f, dy = 1.0f;
    if (x != 160) { float s = __sinf(PI*tx) / (PI*tx); dx = s*s; }
    if (y != 160) { float s = __sinf(PI*ty) / (PI*ty); dy = s*s; }
    float scale = 1.0f / ((float)G2I * dx * dy);
    float accr = 0.f, acci = 0.f;
    #pragma unroll
    for (int c = 0; c < NCI; ++c) {
        float2 g = colimg[((size_t)f*NCI + c)*NPIX + pix];
        float cr = csr[c*NPIX + pix];
        float ci = csi[c*NPIX + pix];
        accr += cr*g.x + ci*g.y;
        acci += cr*g.y - ci*g.x;
    }
    img[(size_t)f*NPIX + pix] = make_float2(accr*scale, acci*scale);
}

// ---------------- warp all frames + sum ----------------
__global__ __launch_bounds__(256) void warp_sum(
    const float2* __restrict__ img, const float* __restrict__ motions,
    float* __restrict__ out)
{
    int pix = blockIdx.x * 256 + threadIdx.x;
    int x = pix / NXI, y = pix - x*NXI;
    float accr = 0.f, acci = 0.f;
    #pragma unroll
    for (int f = 0; f < NTI; ++f) {
        float fx = motions[(size_t)(pix*2 + 0)*NTI + f];
        float fy = motions[(size_t)(pix*2 + 1)*NTI + f];
        float xs = fminf(fmaxf((float)x + fx, 0.0f), (float)(NXI-1));
        float ys = fminf(fmaxf((float)y + fy, 0.0f), (float)(NXI-1));
        int x0 = (int)floorf(xs);
        int y0 = (int)floorf(ys);
        int x1 = min(x0+1, NXI-1);
        int y1 = min(y0+1, NXI-1);
        float dx = xs - (float)x0;
        float dy = ys - (float)y0;
        const float2* im = img + (size_t)f*NPIX;
        float2 v00 = im[x0*NXI + y0];
        float2 v10 = im[x1*NXI + y0];
        float2 v01 = im[x0*NXI + y1];
        float2 v11 = im[x1*NXI + y1];
        float w00 = (1.f-dx)*(1.f-dy), w10 = dx*(1.f-dy);
        float w01 = (1.f-dx)*dy,       w11 = dx*dy;
        accr += w00*v00.x + w10*v10.x + w01*v01.x + w11*v11.x;
        acci += w00*v00.y + w10*v10.y + w01*v01.y + w11*v11.y;
    }
    out[pix*2+0] = accr;
    out[pix*2+1] = acci;
}

extern "C" void kernel_launch(void* const* d_in, const int* in_sizes, int n_in,
                              void* d_out, int out_size, void* d_ws, size_t ws_size,
                              hipStream_t stream)
{
    const float* kr   = (const float*)d_in[0];
    const float* ki   = (const float*)d_in[1];
    const float* traj = (const float*)d_in[2];
    const float* csr  = (const float*)d_in[3];
    const float* csi  = (const float*)d_in[4];
    const float* dcf  = (const float*)d_in[5];
    const float* mot  = (const float*)d_in[6];
    float* out = (float*)d_out;

    char* ws = (char*)d_ws;
    float*  recs     = (float*)ws;                       // 41.94 MB
    ws += (size_t)NTI * MI * REC_F * sizeof(float);
    v2f*    rowout   = (v2f*)ws;                         // 104.86 MB
    ws += (size_t)NTI * NCI * GI * NXI * sizeof(float2);
    float2* colimg   = (float2*)ws;                      // 52.43 MB
    ws += (size_t)NTI * NCI * NPIX * sizeof(float2);
    float2* img      = (float2*)ws;                      // 6.55 MB
    ws += (size_t)NTI * NPIX * sizeof(float2);
    int*    counts   = (int*)ws;  ws += (size_t)NBINS * sizeof(int);        // 13.1 MB
    int*    binstart = (int*)ws;  ws += ((size_t)NBINS + 16) * sizeof(int); // 13.1 MB
    int*    sums     = (int*)ws;  ws += 16384;

    hipMemsetAsync(counts, 0, (size_t)NBINS * sizeof(int), stream);
    count_cells  <<<NTI*MI/256, 256, 0, stream>>>(traj, counts);
    scanA        <<<SCAN_BLKS2, 1024, 0, stream>>>((const int4*)counts,
                                                   (int4*)binstart, sums);
    scanB        <<<1,          1024, 0, stream>>>(sums, binstart);
    scatter_cells<<<NTI*MI/256, 256, 0, stream>>>(kr, ki, traj, dcf, counts,
                                                  binstart, sums, recs);
    row_fft      <<<NTI*GI,     512, 0, stream>>>(binstart, sums, recs, rowout);
    col_fft      <<<NTI*NCI*40, 512, 0, stream>>>(rowout, (v2f*)colimg);
    combine_kernel<<<dim3(NPIX/256, NTI), 256, 0, stream>>>(colimg, csr, csi, img);
    warp_sum     <<<NPIX/256,   256, 0, stream>>>(img, mot, out);
}

// Round 13
// 288.707 us; speedup vs baseline: 1.0316x; 1.0316x over previous
//
#include <hip/hip_runtime.h>
#include <math.h>

#define NXI 320
#define NCI 8
#define NTI 8
#define MI  65536
#define GI  640
#define G2I (GI*GI)
#define NPIX (NXI*NXI)
#define REC_F 20          // floats per record: {du,dv,0,0, 8x(re,im)}
#define NBINS (NTI*G2I)   // 3,276,800 cells over all frames
#define SCAN_BLKS2 (NBINS/4096)   // 800 (4096 bins per block)

typedef float v2f __attribute__((ext_vector_type(2)));

__device__ inline v2f cmul(v2f a, v2f b) {
    v2f axx = __builtin_shufflevector(a, a, 0, 0);
    v2f ayy = __builtin_shufflevector(a, a, 1, 1);
    v2f byx = __builtin_shufflevector(b, b, 1, 0);
    v2f r = axx * b;
    v2f t = ayy * byx;
    return r + v2f{-t.x, t.y};
}

__device__ inline v2f shfl_xor_v(v2f v, int m) {
    return v2f{__shfl_xor(v.x, m, 64), __shfl_xor(v.y, m, 64)};
}

__device__ inline void cell_from_uv(float tu, float tv,
                                    int& i0s, int& j0s, float& du, float& dv)
{
    float u = (tu + 0.5f) * (float)GI;
    float v = (tv + 0.5f) * (float)GI;
    float fu = floorf(u), fv = floorf(v);
    du = u - fu; dv = v - fv;
    i0s = (int)fu + GI/2; if (i0s >= GI) i0s -= GI;   // ifftshift folded in
    j0s = (int)fv + GI/2; if (j0s >= GI) j0s -= GI;
}

// ---------------- count: one thread per sample m, loop over frames ----------------
__global__ __launch_bounds__(256) void count_cells(
    const float4* __restrict__ traj4, int* __restrict__ counts)
{
    int m = blockIdx.x * 256 + threadIdx.x;
    float4 t0 = traj4[m*4+0], t1 = traj4[m*4+1];   // u[0..7]
    float4 t2 = traj4[m*4+2], t3 = traj4[m*4+3];   // v[0..7]
    float u[8] = {t0.x,t0.y,t0.z,t0.w, t1.x,t1.y,t1.z,t1.w};
    float v[8] = {t2.x,t2.y,t2.z,t2.w, t3.x,t3.y,t3.z,t3.w};
    #pragma unroll
    for (int f = 0; f < NTI; ++f) {
        int i0s, j0s; float du, dv;
        cell_from_uv(u[f], v[f], i0s, j0s, du, dv);
        atomicAdd(&counts[f*G2I + i0s*GI + j0s], 1);
    }
}

__device__ inline int wave_incl_scan(int v, int lane) {
    #pragma unroll
    for (int d = 1; d < 64; d <<= 1) {
        int y = __shfl_up(v, d, 64);
        if (lane >= d) v += y;
    }
    return v;
}

// 4096 bins per block, barrier-light: wave shuffle scan + 16-entry cross-wave
__global__ __launch_bounds__(1024) void scanA(const int4* __restrict__ counts4,
                                              int4* __restrict__ binstart4,
                                              int* __restrict__ sums)
{
    __shared__ int wtot[16];
    int tid = threadIdx.x, lane = tid & 63, wv = tid >> 6;
    int i = blockIdx.x * 1024 + tid;
    int4 c = counts4[i];
    int s = c.x + c.y + c.z + c.w;
    int incl = wave_incl_scan(s, lane);
    if (lane == 63) wtot[wv] = incl;
    __syncthreads();
    if (wv == 0 && lane < 16) {
        int t = wtot[lane];
        #pragma unroll
        for (int d = 1; d < 16; d <<= 1) {
            int y = __shfl_up(t, d, 64);
            if (lane >= d) t += y;
        }
        wtot[lane] = t;     // inclusive over waves
    }
    __syncthreads();
    int woff = wv ? wtot[wv - 1] : 0;
    int excl = woff + incl - s;
    int4 b;
    b.x = excl; b.y = excl + c.x; b.z = b.y + c.y; b.w = b.z + c.z;
    binstart4[i] = b;
    if (tid == 1023) sums[blockIdx.x] = woff + incl;   // block total
}

// one block: exclusive scan of the 800 chunk sums + sentinels
__global__ __launch_bounds__(1024) void scanB(int* __restrict__ sums,
                                              int* __restrict__ binstart)
{
    __shared__ int tmp[1024];
    int tid = threadIdx.x;
    int v = (tid < SCAN_BLKS2) ? sums[tid] : 0;
    tmp[tid] = v; __syncthreads();
    for (int d = 1; d < 1024; d <<= 1) {
        int y = (tid >= d) ? tmp[tid - d] : 0;
        __syncthreads();
        tmp[tid] += y;
        __syncthreads();
    }
    int incl = tmp[tid];
    if (tid < SCAN_BLKS2) sums[tid] = incl - v;
    if (tid == SCAN_BLKS2 - 1) {
        sums[SCAN_BLKS2] = incl;        // == grand total: sentinel chunk
        binstart[NBINS] = 0;            // so GS(NBINS) == total
    }
}

// ---- scatter: one thread per sample m, loop over frames; kr/ki loaded ONCE ----
__global__ __launch_bounds__(256) void scatter_cells(
    const float* __restrict__ kr, const float* __restrict__ ki,
    const float4* __restrict__ traj4, const float4* __restrict__ dcf4,
    int* __restrict__ counts, const int* __restrict__ binstart,
    const int* __restrict__ sums, float* __restrict__ recs)
{
    int m = blockIdx.x * 256 + threadIdx.x;
    float4 t0 = traj4[m*4+0], t1 = traj4[m*4+1];
    float4 t2 = traj4[m*4+2], t3 = traj4[m*4+3];
    float4 d0 = dcf4[m*2+0],  d1 = dcf4[m*2+1];
    float u[8]  = {t0.x,t0.y,t0.z,t0.w, t1.x,t1.y,t1.z,t1.w};
    float v[8]  = {t2.x,t2.y,t2.z,t2.w, t3.x,t3.y,t3.z,t3.w};
    float dd[8] = {d0.x,d0.y,d0.z,d0.w, d1.x,d1.y,d1.z,d1.w};
    float re[8], im[8];
    #pragma unroll
    for (int c = 0; c < NCI; ++c) {
        re[c] = kr[c*MI + m];
        im[c] = ki[c*MI + m];
    }
    #pragma unroll
    for (int f = 0; f < NTI; ++f) {
        int i0s, j0s; float du, dv;
        cell_from_uv(u[f], v[f], i0s, j0s, du, dv);
        float w = dd[f];
        int bin = f*G2I + i0s*GI + j0s;
        int within = atomicSub(&counts[bin], 1) - 1;
        int slot = binstart[bin] + sums[bin >> 12] + within;
        float4* r = (float4*)(recs + (size_t)slot * REC_F);
        r[0] = make_float4(du, dv, 0.f, 0.f);
        #pragma unroll
        for (int q = 0; q < 4; ++q) {
            int c0 = 2*q;
            r[1+q] = make_float4(re[c0]*w,   im[c0]*w,
                                 re[c0+1]*w, im[c0+1]*w);
        }
    }
}

// ---------------- register-resident 640-pt iFFT (sign +), packed ----------------
__device__ inline void dft5p(v2f x0, v2f x1, v2f x2, v2f x3, v2f x4, v2f* X)
{
    const float c1 = 0.309016994f, c2 = -0.809016994f;
    const float s1 = 0.951056516f, s2 =  0.587785252f;
    v2f S1 = x1 + x4, D1 = x1 - x4;
    v2f S2 = x2 + x3, D2 = x2 - x3;
    X[0] = x0 + S1 + S2;
    v2f A = x0 + c1*S1 + c2*S2;
    v2f T = s1*D1 + s2*D2;
    v2f B = x0 + c2*S1 + c1*S2;
    v2f U = s2*D1 - s1*D2;
    v2f iT = v2f{-T.y, T.x};
    v2f iU = v2f{-U.y, U.x};
    X[1] = A + iT;  X[4] = A - iT;
    X[2] = B + iU;  X[3] = B - iU;
}

__device__ inline void fft640_pruned(v2f* a, int lane, v2f* line, int xorm)
{
    const float PI = 3.14159265358979f;
    // 6 across-lane DIF stages: t = p + sg*a (pk_fma), then cmul by
    // hoisted per-lane w (w=1 for low lanes). r5-verified sign convention.
    #pragma unroll
    for (int s = 0; s < 6; ++s) {
        const int h = 32 >> s;
        bool low = (lane & h) == 0;
        int kp = (lane << s) & 31;
        float sn, cs;
        __sincosf((2.0f * PI / 64.0f) * (float)kp, &sn, &cs);
        v2f w = low ? v2f{1.f, 0.f} : v2f{cs, sn};
        float sg = low ? 1.f : -1.f;
        v2f sgv = v2f{sg, sg};
        #pragma unroll
        for (int n = 0; n < 10; ++n) {
            v2f p = shfl_xor_v(a[n], h);
            v2f t = sgv * a[n] + p;        // low: p+a ; high: p-a
            a[n] = cmul(t, w);
        }
    }
    int k1 = __brev(lane) >> 26;
    float th2 = (2.0f * PI / 640.0f) * (float)k1;
    float sn, cs;
    __sincosf(th2, &sn, &cs);
    v2f wb = v2f{cs, sn};
    v2f w = wb;
    #pragma unroll
    for (int n = 1; n < 10; ++n) {
        a[n] = cmul(a[n], w);
        w = cmul(w, wb);
    }
    v2f E[5], O[5];
    dft5p(a[0], a[2], a[4], a[6], a[8], E);
    dft5p(a[1], a[3], a[5], a[7], a[9], O);
    const v2f tk1 = { 0.809016994f, 0.587785252f};
    const v2f tk2 = { 0.309016994f, 0.951056516f};
    const v2f tk3 = {-0.309016994f, 0.951056516f};
    const v2f tk4 = {-0.809016994f, 0.587785252f};
    v2f t1 = cmul(tk1, O[1]);
    v2f t2 = cmul(tk2, O[2]);
    v2f t3 = cmul(tk3, O[3]);
    v2f t4 = cmul(tk4, O[4]);
    bool hi = (k1 >= 32);
    line[(160 + k1) ^ xorm] = E[0] + O[0];          // k2=0
    line[(224 + k1) ^ xorm] = E[1] + t1;            // k2=1
    int yx = hi ? (k1 - 32) : (288 + k1);           // k2=7 : k2=2
    v2f zx = hi ? (E[2] - t2) : (E[2] + t2);
    line[yx ^ xorm] = zx;
    line[(32 + k1) ^ xorm] = E[3] - t3;             // k2=8
    line[(96 + k1) ^ xorm] = E[4] - t4;             // k2=9
}

// ---- fused atomic-free gather + row FFT: block = (frame, grid-row i) ----
// gather mapping: j = tid (+512) — measured fastest (r8/r10); full-width
// first pass for all waves, short second pass for waves 0-1 only.
__global__ __launch_bounds__(512, 8) void row_fft(
    const int* __restrict__ binstart, const int* __restrict__ sums,
    const float* __restrict__ recs, v2f* __restrict__ rowout)
{
    __shared__ v2f A[NCI][GI];      // 40,960 B exactly -> 4 blocks/CU
    int bid = blockIdx.x;           // f*GI + i
    int i = bid % GI;
    int f = bid / GI;
    int tid = threadIdx.x;
    int im1 = i ? i - 1 : GI - 1;
    const int base0 = f*G2I + i*GI;     // p=0: row i   (1-du)
    const int base1 = f*G2I + im1*GI;   // p=1: row i-1 (du)

    #define GS(b) (binstart[b] + sums[(b) >> 12])

    for (int j = tid; j < GI; j += 512) {
        v2f acc[NCI];
        #pragma unroll
        for (int c = 0; c < NCI; ++c) acc[c] = v2f{0.f, 0.f};
        #pragma unroll
        for (int p = 0; p < 2; ++p) {
            const int base = p ? base1 : base0;
            if (j > 0) {
                int lo = GS(base + j - 1), mid = GS(base + j), hi = GS(base + j + 1);
                for (int s = lo; s < hi; ++s) {
                    const float4* R = (const float4*)(recs + (size_t)s*REC_F);
                    float4 h4 = R[0];
                    float wr = p ? h4.x : (1.f - h4.x);
                    float w  = wr * ((s < mid) ? h4.y : (1.f - h4.y));
                    float4 d0 = R[1], d1 = R[2], d2 = R[3], d3 = R[4];
                    acc[0] += w * v2f{d0.x, d0.y};  acc[1] += w * v2f{d0.z, d0.w};
                    acc[2] += w * v2f{d1.x, d1.y};  acc[3] += w * v2f{d1.z, d1.w};
                    acc[4] += w * v2f{d2.x, d2.y};  acc[5] += w * v2f{d2.z, d2.w};
                    acc[6] += w * v2f{d3.x, d3.y};  acc[7] += w * v2f{d3.z, d3.w};
                }
            } else {
                #pragma unroll
                for (int side = 0; side < 2; ++side) {
                    int b = base + (side ? 0 : (GI - 1));
                    int s0 = GS(b), s1 = GS(b + 1);
                    for (int s = s0; s < s1; ++s) {
                        const float4* R = (const float4*)(recs + (size_t)s*REC_F);
                        float4 h4 = R[0];
                        float wr = p ? h4.x : (1.f - h4.x);
                        float w  = wr * (side ? (1.f - h4.y) : h4.y);
                        float4 d0 = R[1], d1 = R[2], d2 = R[3], d3 = R[4];
                        acc[0] += w * v2f{d0.x, d0.y};  acc[1] += w * v2f{d0.z, d0.w};
                        acc[2] += w * v2f{d1.x, d1.y};  acc[3] += w * v2f{d1.z, d1.w};
                        acc[4] += w * v2f{d2.x, d2.y};  acc[5] += w * v2f{d2.z, d2.w};
                        acc[6] += w * v2f{d3.x, d3.y};  acc[7] += w * v2f{d3.z, d3.w};
                    }
                }
            }
        }
        #pragma unroll
        for (int c = 0; c < NCI; ++c) A[c][j] = acc[c];
    }
    #undef GS
    __syncthreads();

    int wv = tid >> 6, lane = tid & 63;
    v2f a[10];
    #pragma unroll
    for (int n = 0; n < 10; ++n) a[n] = A[wv][10*lane + n];
    fft640_pruned(a, lane, A[wv], 0);
    v2f* dst = rowout + (((size_t)f*NCI + wv)*GI + i)*NXI;
    #pragma unroll
    for (int q = 0; q < 5; ++q) {
        int yc = lane + 64*q;
        dst[yc] = A[wv][yc];
    }
}

// ---- col FFT + crop: block = (frame, coil, y-group of 8) ----
__global__ __launch_bounds__(512, 8) void col_fft(
    const v2f* __restrict__ rowout, v2f* __restrict__ colimg)
{
    __shared__ v2f A[8][GI];
    int bid = blockIdx.x;
    int g = bid % 40;
    int c = (bid / 40) % NCI;
    int f = bid / (40*NCI);
    int y0 = g * 8;
    int tid = threadIdx.x;
    const v2f* src = rowout + ((size_t)f*NCI + c)*GI*NXI + y0;
    for (int idx = tid; idx < 8*GI; idx += 512) {
        int l = idx & 7, k = idx >> 3;
        A[l][k ^ (4*(l & 3))] = src[(size_t)k*NXI + l];
    }
    __syncthreads();
    int wv = tid >> 6, lane = tid & 63;
    int xm = 4 * (wv & 3);
    v2f a[10];
    #pragma unroll
    for (int n = 0; n < 10; ++n) a[n] = A[wv][(10*lane + n) ^ xm];
    fft640_pruned(a, lane, A[wv], xm);
    __syncthreads();
    v2f* dst = colimg + ((size_t)f*NCI + c)*NPIX + y0;
    for (int idx = tid; idx < 8*NXI; idx += 512) {
        int l = idx & 7, xx = idx >> 3;
        dst[(size_t)xx*NXI + l] = A[l][xx ^ (4*(l & 3))];
    }
}

// ------------- deapodize + coil combine -------------
__global__ __launch_bounds__(256) void combine_kernel(
    const float2* __restrict__ colimg, const float* __restrict__ csr,
    const float* __restrict__ csi, float2* __restrict__ img)
{
    int f = blockIdx.y;
    int pix = blockIdx.x * 256 + threadIdx.x;
    int x = pix / NXI, y = pix - x*NXI;
    const float PI = 3.14159265358979f;
    float tx = (x - 160) * (1.0f/GI);
    float ty = (y - 160) * (1.0f/GI);
    float dx = 1.0f, dy = 1.0f;
    if (x != 160) { float s = __sinf(PI*tx) / (PI*tx); dx = s*s; }
    if (y != 160) { float s = __sinf(PI*ty) / (PI*ty); dy = s*s; }
    float scale = 1.0f / ((float)G2I * dx * dy);
    float accr = 0.f, acci = 0.f;
    #pragma unroll
    for (int c = 0; c < NCI; ++c) {
        float2 g = colimg[((size_t)f*NCI + c)*NPIX + pix];
        float cr = csr[c*NPIX + pix];
        float ci = csi[c*NPIX + pix];
        accr += cr*g.x + ci*g.y;
        acci += cr*g.y - ci*g.x;
    }
    img[(size_t)f*NPIX + pix] = make_float2(accr*scale, acci*scale);
}

// ---------------- warp all frames + sum ----------------
__global__ __launch_bounds__(256) void warp_sum(
    const float2* __restrict__ img, const float* __restrict__ motions,
    float* __restrict__ out)
{
    int pix = blockIdx.x * 256 + threadIdx.x;
    int x = pix / NXI, y = pix - x*NXI;
    float accr = 0.f, acci = 0.f;
    #pragma unroll
    for (int f = 0; f < NTI; ++f) {
        float fx = motions[(size_t)(pix*2 + 0)*NTI + f];
        float fy = motions[(size_t)(pix*2 + 1)*NTI + f];
        float xs = fminf(fmaxf((float)x + fx, 0.0f), (float)(NXI-1));
        float ys = fminf(fmaxf((float)y + fy, 0.0f), (float)(NXI-1));
        int x0 = (int)floorf(xs);
        int y0 = (int)floorf(ys);
        int x1 = min(x0+1, NXI-1);
        int y1 = min(y0+1, NXI-1);
        float dx = xs - (float)x0;
        float dy = ys - (float)y0;
        const float2* im = img + (size_t)f*NPIX;
        float2 v00 = im[x0*NXI + y0];
        float2 v10 = im[x1*NXI + y0];
        float2 v01 = im[x0*NXI + y1];
        float2 v11 = im[x1*NXI + y1];
        float w00 = (1.f-dx)*(1.f-dy), w10 = dx*(1.f-dy);
        float w01 = (1.f-dx)*dy,       w11 = dx*dy;
        accr += w00*v00.x + w10*v10.x + w01*v01.x + w11*v11.x;
        acci += w00*v00.y + w10*v10.y + w01*v01.y + w11*v11.y;
    }
    out[pix*2+0] = accr;
    out[pix*2+1] = acci;
}

extern "C" void kernel_launch(void* const* d_in, const int* in_sizes, int n_in,
                              void* d_out, int out_size, void* d_ws, size_t ws_size,
                              hipStream_t stream)
{
    const float* kr   = (const float*)d_in[0];
    const float* ki   = (const float*)d_in[1];
    const float* traj = (const float*)d_in[2];
    const float* csr  = (const float*)d_in[3];
    const float* csi  = (const float*)d_in[4];
    const float* dcf  = (const float*)d_in[5];
    const float* mot  = (const float*)d_in[6];
    float* out = (float*)d_out;

    char* ws = (char*)d_ws;
    float*  recs     = (float*)ws;                       // 41.94 MB
    ws += (size_t)NTI * MI * REC_F * sizeof(float);
    v2f*    rowout   = (v2f*)ws;                         // 104.86 MB
    ws += (size_t)NTI * NCI * GI * NXI * sizeof(float2);
    float2* colimg   = (float2*)ws;                      // 52.43 MB
    ws += (size_t)NTI * NCI * NPIX * sizeof(float2);
    float2* img      = (float2*)ws;                      // 6.55 MB
    ws += (size_t)NTI * NPIX * sizeof(float2);
    int*    counts   = (int*)ws;  ws += (size_t)NBINS * sizeof(int);        // 13.1 MB
    int*    binstart = (int*)ws;  ws += ((size_t)NBINS + 16) * sizeof(int); // 13.1 MB
    int*    sums     = (int*)ws;  ws += 16384;

    hipMemsetAsync(counts, 0, (size_t)NBINS * sizeof(int), stream);
    count_cells  <<<MI/256,     256, 0, stream>>>((const float4*)traj, counts);
    scanA        <<<SCAN_BLKS2, 1024, 0, stream>>>((const int4*)counts,
                                                   (int4*)binstart, sums);
    scanB        <<<1,          1024, 0, stream>>>(sums, binstart);
    scatter_cells<<<MI/256,     256, 0, stream>>>(kr, ki, (const float4*)traj,
                                                  (const float4*)dcf, counts,
                                                  binstart, sums, recs);
    row_fft      <<<NTI*GI,     512, 0, stream>>>(binstart, sums, recs, rowout);
    col_fft      <<<NTI*NCI*40, 512, 0, stream>>>(rowout, (v2f*)colimg);
    combine_kernel<<<dim3(NPIX/256, NTI), 256, 0, stream>>>(colimg, csr, csi, img);
    warp_sum     <<<NPIX/256,   256, 0, stream>>>(img, mot, out);
}